// Round 11
// baseline (32501.901 us; speedup 1.0000x reference)
//
#include <hip/hip_runtime.h>

#define T_STEPS 8192
#define DD 1024
#define HH 1024
#define NWG 256
#define NTHR 512
#define SCOPE_AGENT __HIP_MEMORY_SCOPE_AGENT
#define SCOPE_WG __HIP_MEMORY_SCOPE_WORKGROUP
typedef unsigned long long u64;

// XOR swizzle (float index): 4-aligned groups move as units; the 4 seg-groups
// of a wave's b128 broadcast reads hit distinct bank quads (proven 0-conflict).
__device__ __forceinline__ int swz(int k) { return k ^ ((((k) >> 6) & 3) << 2); }

__device__ __forceinline__ float ftanh(float v) {
  return 2.f / (1.f + __expf(-2.f * v)) - 1.f;
}

// Persistent scan, per-element tail. WG g owns h[4g..4g+4).
//   x-waves 0-3: stage OWN 256-float xb chunk (wave-private, lgkm only),
//     x-dot for all 16 columns over that chunk, partial row + pflag. No
//     barrier between them and the h critical path except the one per-step
//     __syncthreads guarding LDS buffer reuse.
//   h-waves 4-7: wave 4+e polls its 256-atom h chunk (tagged 8B atoms,
//     2-slot ping-pong), stages hb, h-dot, partial row + pflag, then spins
//     the 8 LDS flags, computes gates for ITS OWN element e (lanes 0-3,
//     uniform-activation), publishes its tagged atom BEFORE the barrier.
// Flags are step-tagged (monotone) so they never need resetting; one
// __syncthreads per step guards partial/xb/hb overwrite for the next step.
__global__ __launch_bounds__(NTHR, 1) void lstm_scan(
    const float* __restrict__ x, const float* __restrict__ c_in,
    const float* __restrict__ h_in, const float* __restrict__ W,
    const float* __restrict__ b, float* __restrict__ Hs,  // [T][H] = h_1..h_T
    u64* __restrict__ hbuf,         // [2][H] tagged ping-pong (memset 0)
    float* __restrict__ out_tail)   // c_last | h_last
{
  const int g = blockIdx.x, tid = threadIdx.x;
  const int lane = tid & 63, wave = tid >> 6;
  const int col = tid & 15, seg = tid >> 4;
  const int gate = col >> 2, hi = col & 3;
  const int cg = gate * HH + g * 4 + hi;

  __shared__ float Wl[32768];       // 128 KB packed weights (16 KB/wave)
  __shared__ float xb[DD];          // swizzled x_t (x-wave-private chunks)
  __shared__ float hb[HH];          // swizzled h_{t-1} (h-wave-private chunks)
  __shared__ float partial[8][16];  // per-wave column partials
  __shared__ int pflag[8];          // step-tagged "partial row ready"

  if (tid < 8) pflag[tid] = 0;
  if (tid < 4) {
    const float h0 = h_in[g * 4 + tid];
    const u64 pv = ((u64)1u << 32) | (u64)__float_as_uint(h0);
    __hip_atomic_store(&hbuf[g * 4 + tid], pv, __ATOMIC_RELAXED, SCOPE_AGENT);
  }

  // One-time weight staging (identical to r7; each wave stages the 16 KB its
  // own dot reads, packed so ds_read_b128 is a contiguous 1 KB wave read).
  #pragma unroll
  for (int j = 0; j < 16; ++j) {
    float4 v;
    v.x = W[(size_t)(seg * 64 + j * 4 + 0) * (4 * HH) + cg];
    v.y = W[(size_t)(seg * 64 + j * 4 + 1) * (4 * HH) + cg];
    v.z = W[(size_t)(seg * 64 + j * 4 + 2) * (4 * HH) + cg];
    v.w = W[(size_t)(seg * 64 + j * 4 + 3) * (4 * HH) + cg];
    *(float4*)&Wl[(wave * 16 + j) * 256 + lane * 4] = v;
  }

  const bool is_x = (wave < 4);

  if (is_x) {
    // ---------------- x-wave ----------------
    const int sw = (seg & 3) << 2;
    float4 xq = *(const float4*)&x[wave * 256 + lane * 4];  // x_1 prefetch
    __syncthreads();  // Wl + pflag + h0-publish ready

    for (int t = 1; t <= T_STEPS; ++t) {
      // Stage own xb chunk (wave-private; float4 stays contiguous under swz).
      *(float4*)&xb[swz(wave * 256 + lane * 4)] = xq;
      if (t < T_STEPS)
        xq = *(const float4*)&x[(size_t)t * DD + wave * 256 + lane * 4];
      asm volatile("s_waitcnt lgkmcnt(0)" ::: "memory");
      // x-dot, 4-way split accumulators (16-deep chains instead of 64).
      float q0 = 0.f, q1 = 0.f, q2 = 0.f, q3 = 0.f;
      #pragma unroll
      for (int j4 = 0; j4 < 4; ++j4) {
        {
          const int j = j4 * 4 + 0;
          const float4 wv = *(const float4*)&Wl[(wave * 16 + j) * 256 + lane * 4];
          const float4 xv = *(const float4*)&xb[(seg * 64 + j * 4) ^ sw];
          q0 = fmaf(xv.x, wv.x, q0); q0 = fmaf(xv.y, wv.y, q0);
          q0 = fmaf(xv.z, wv.z, q0); q0 = fmaf(xv.w, wv.w, q0);
        }
        {
          const int j = j4 * 4 + 1;
          const float4 wv = *(const float4*)&Wl[(wave * 16 + j) * 256 + lane * 4];
          const float4 xv = *(const float4*)&xb[(seg * 64 + j * 4) ^ sw];
          q1 = fmaf(xv.x, wv.x, q1); q1 = fmaf(xv.y, wv.y, q1);
          q1 = fmaf(xv.z, wv.z, q1); q1 = fmaf(xv.w, wv.w, q1);
        }
        {
          const int j = j4 * 4 + 2;
          const float4 wv = *(const float4*)&Wl[(wave * 16 + j) * 256 + lane * 4];
          const float4 xv = *(const float4*)&xb[(seg * 64 + j * 4) ^ sw];
          q2 = fmaf(xv.x, wv.x, q2); q2 = fmaf(xv.y, wv.y, q2);
          q2 = fmaf(xv.z, wv.z, q2); q2 = fmaf(xv.w, wv.w, q2);
        }
        {
          const int j = j4 * 4 + 3;
          const float4 wv = *(const float4*)&Wl[(wave * 16 + j) * 256 + lane * 4];
          const float4 xv = *(const float4*)&xb[(seg * 64 + j * 4) ^ sw];
          q3 = fmaf(xv.x, wv.x, q3); q3 = fmaf(xv.y, wv.y, q3);
          q3 = fmaf(xv.z, wv.z, q3); q3 = fmaf(xv.w, wv.w, q3);
        }
      }
      float p = (q0 + q1) + (q2 + q3);
      p += __shfl_xor(p, 16);
      p += __shfl_xor(p, 32);
      if (lane < 16) partial[wave][lane] = p;
      asm volatile("s_waitcnt lgkmcnt(0)" ::: "memory");
      if (lane == 0)
        __hip_atomic_store(&pflag[wave], t, __ATOMIC_RELAXED, SCOPE_WG);
      __syncthreads();  // buffer-reuse fence for step t+1
    }
  } else {
    // ---------------- h-wave ----------------
    const int e = wave - 4;
    const int cb = e * 256;
    const int s2 = seg - 16;
    const int sw2 = (s2 & 3) << 2;
    const float biasF = (lane < 4) ? b[lane * HH + g * 4 + e] : 0.f;
    float c_reg = (lane == 0) ? c_in[g * 4 + e] : 0.f;
    float hlast = 0.f;
    __syncthreads();  // Wl + pflag + h0-publish ready

    for (int t = 1; t <= T_STEPS; ++t) {
      // C: poll own 256-atom chunk (4/lane); sleep-throttled stale retry.
      const u64* hp = hbuf + ((t - 1) & 1) * HH;
      const unsigned tg = (unsigned)t;
      u64 a0 = __hip_atomic_load(&hp[cb + lane],       __ATOMIC_RELAXED, SCOPE_AGENT);
      u64 a1 = __hip_atomic_load(&hp[cb + 64 + lane],  __ATOMIC_RELAXED, SCOPE_AGENT);
      u64 a2 = __hip_atomic_load(&hp[cb + 128 + lane], __ATOMIC_RELAXED, SCOPE_AGENT);
      u64 a3 = __hip_atomic_load(&hp[cb + 192 + lane], __ATOMIC_RELAXED, SCOPE_AGENT);
      bool r0 = (unsigned)(a0 >> 32) >= tg;
      bool r1 = (unsigned)(a1 >> 32) >= tg;
      bool r2 = (unsigned)(a2 >> 32) >= tg;
      bool r3 = (unsigned)(a3 >> 32) >= tg;
      while (!(r0 & r1 & r2 & r3)) {
        __builtin_amdgcn_s_sleep(1);
        if (!r0) { a0 = __hip_atomic_load(&hp[cb + lane],       __ATOMIC_RELAXED, SCOPE_AGENT); r0 = (unsigned)(a0 >> 32) >= tg; }
        if (!r1) { a1 = __hip_atomic_load(&hp[cb + 64 + lane],  __ATOMIC_RELAXED, SCOPE_AGENT); r1 = (unsigned)(a1 >> 32) >= tg; }
        if (!r2) { a2 = __hip_atomic_load(&hp[cb + 128 + lane], __ATOMIC_RELAXED, SCOPE_AGENT); r2 = (unsigned)(a2 >> 32) >= tg; }
        if (!r3) { a3 = __hip_atomic_load(&hp[cb + 192 + lane], __ATOMIC_RELAXED, SCOPE_AGENT); r3 = (unsigned)(a3 >> 32) >= tg; }
      }
      hb[swz(cb + lane)]       = __uint_as_float((unsigned)a0);
      hb[swz(cb + 64 + lane)]  = __uint_as_float((unsigned)a1);
      hb[swz(cb + 128 + lane)] = __uint_as_float((unsigned)a2);
      hb[swz(cb + 192 + lane)] = __uint_as_float((unsigned)a3);
      asm volatile("s_waitcnt lgkmcnt(0)" ::: "memory");
      // D: h-dot over own chunk, 4-way split accumulators.
      float q0 = 0.f, q1 = 0.f, q2 = 0.f, q3 = 0.f;
      #pragma unroll
      for (int j4 = 0; j4 < 4; ++j4) {
        {
          const int j = j4 * 4 + 0;
          const float4 wv = *(const float4*)&Wl[(wave * 16 + j) * 256 + lane * 4];
          const float4 hv = *(const float4*)&hb[(s2 * 64 + j * 4) ^ sw2];
          q0 = fmaf(hv.x, wv.x, q0); q0 = fmaf(hv.y, wv.y, q0);
          q0 = fmaf(hv.z, wv.z, q0); q0 = fmaf(hv.w, wv.w, q0);
        }
        {
          const int j = j4 * 4 + 1;
          const float4 wv = *(const float4*)&Wl[(wave * 16 + j) * 256 + lane * 4];
          const float4 hv = *(const float4*)&hb[(s2 * 64 + j * 4) ^ sw2];
          q1 = fmaf(hv.x, wv.x, q1); q1 = fmaf(hv.y, wv.y, q1);
          q1 = fmaf(hv.z, wv.z, q1); q1 = fmaf(hv.w, wv.w, q1);
        }
        {
          const int j = j4 * 4 + 2;
          const float4 wv = *(const float4*)&Wl[(wave * 16 + j) * 256 + lane * 4];
          const float4 hv = *(const float4*)&hb[(s2 * 64 + j * 4) ^ sw2];
          q2 = fmaf(hv.x, wv.x, q2); q2 = fmaf(hv.y, wv.y, q2);
          q2 = fmaf(hv.z, wv.z, q2); q2 = fmaf(hv.w, wv.w, q2);
        }
        {
          const int j = j4 * 4 + 3;
          const float4 wv = *(const float4*)&Wl[(wave * 16 + j) * 256 + lane * 4];
          const float4 hv = *(const float4*)&hb[(s2 * 64 + j * 4) ^ sw2];
          q3 = fmaf(hv.x, wv.x, q3); q3 = fmaf(hv.y, wv.y, q3);
          q3 = fmaf(hv.z, wv.z, q3); q3 = fmaf(hv.w, wv.w, q3);
        }
      }
      float q = (q0 + q1) + (q2 + q3);
      q += __shfl_xor(q, 16);
      q += __shfl_xor(q, 32);
      if (lane < 16) partial[wave][lane] = q;
      asm volatile("s_waitcnt lgkmcnt(0)" ::: "memory");
      if (lane == 0)
        __hip_atomic_store(&pflag[wave], t, __ATOMIC_RELAXED, SCOPE_WG);
      // F: spin the 8 LDS flags (x flags long set; last h-wave gates).
      for (;;) {
        const int f0 = __hip_atomic_load(&pflag[0], __ATOMIC_RELAXED, SCOPE_WG);
        const int f1 = __hip_atomic_load(&pflag[1], __ATOMIC_RELAXED, SCOPE_WG);
        const int f2 = __hip_atomic_load(&pflag[2], __ATOMIC_RELAXED, SCOPE_WG);
        const int f3 = __hip_atomic_load(&pflag[3], __ATOMIC_RELAXED, SCOPE_WG);
        const int f4 = __hip_atomic_load(&pflag[4], __ATOMIC_RELAXED, SCOPE_WG);
        const int f5 = __hip_atomic_load(&pflag[5], __ATOMIC_RELAXED, SCOPE_WG);
        const int f6 = __hip_atomic_load(&pflag[6], __ATOMIC_RELAXED, SCOPE_WG);
        const int f7 = __hip_atomic_load(&pflag[7], __ATOMIC_RELAXED, SCOPE_WG);
        if (f0 >= t && f1 >= t && f2 >= t && f3 >= t &&
            f4 >= t && f5 >= t && f6 >= t && f7 >= t) break;
      }
      // Gates for element e on lanes 0-3 (lane = gate; order i,j,f,o).
      float act = 0.f;
      if (lane < 4) {
        const int ci = lane * 4 + e;
        const float s01 = partial[0][ci] + partial[1][ci];
        const float s23 = partial[2][ci] + partial[3][ci];
        const float s45 = partial[4][ci] + partial[5][ci];
        const float s67 = partial[6][ci] + partial[7][ci];
        const float z = biasF + ((s01 + s23) + (s45 + s67));
        const float zin = (lane == 1) ? (2.f * z) : (lane == 2 ? z + 1.f : z);
        const float s = 1.f / (1.f + __expf(-zin));
        act = (lane == 1) ? (2.f * s - 1.f) : s;
      }
      const float ig = __shfl(act, 0);
      const float tj = __shfl(act, 1);
      const float fg = __shfl(act, 2);
      const float og = __shfl(act, 3);
      if (lane == 0) {
        const float nc = c_reg * fg + ig * tj;
        const float nh = ftanh(nc) * og;
        c_reg = nc; hlast = nh;
        const u64 pv = ((u64)(unsigned)(t + 1) << 32) | (u64)__float_as_uint(nh);
        __hip_atomic_store(&hbuf[(t & 1) * HH + g * 4 + e], pv,
                           __ATOMIC_RELAXED, SCOPE_AGENT);   // publish FIRST
        Hs[(size_t)(t - 1) * HH + g * 4 + e] = nh;           // then history
      }
      __syncthreads();  // buffer-reuse fence for step t+1
    }
    if (lane == 0) {
      out_tail[g * 4 + e]      = c_reg;   // c_last
      out_tail[HH + g * 4 + e] = hlast;   // h_last
    }
  }
}

// output = hs @ W_out + b_out. fp32 GEMM, 128x128 tile, 8x8/thread, BK=16.
// (r10 proven: per-float4 involution swizzle on Bs; As transposed.)
#define BM 128
#define BN 128
#define BK 16
__device__ __forceinline__ int bswz(int c) { return c ^ (((c >> 5) & 1) << 2); }

__global__ __launch_bounds__(256, 2) void out_gemm(
    const float* __restrict__ A,    // hs [8192][1024]
    const float* __restrict__ Bw,   // W_out [1024][1024]
    const float* __restrict__ bias,
    float* __restrict__ C)          // [8192][1024]
{
  __shared__ float As[BK][BM + 4];
  __shared__ float Bs[BK][BN + 4];
  const int tid = threadIdx.x;
  const int row0 = blockIdx.y * BM, col0 = blockIdx.x * BN;
  const int tx = tid & 15, ty = tid >> 4;

  const int ar = tid >> 1;
  const int ac = (tid & 1) * 8;
  const int br = tid >> 4;
  const int bc = (tid & 15) * 8;

  float acc[8][8];
  #pragma unroll
  for (int i = 0; i < 8; ++i)
    #pragma unroll
    for (int j = 0; j < 8; ++j) acc[i][j] = 0.f;

  for (int k0 = 0; k0 < HH; k0 += BK) {
    const float4 a0 = *(const float4*)&A[(size_t)(row0 + ar) * HH + k0 + ac];
    const float4 a1 = *(const float4*)&A[(size_t)(row0 + ar) * HH + k0 + ac + 4];
    const float4 b0 = *(const float4*)&Bw[(size_t)(k0 + br) * HH + col0 + bc];
    const float4 b1 = *(const float4*)&Bw[(size_t)(k0 + br) * HH + col0 + bc + 4];
    As[ac + 0][ar] = a0.x; As[ac + 1][ar] = a0.y;
    As[ac + 2][ar] = a0.z; As[ac + 3][ar] = a0.w;
    As[ac + 4][ar] = a1.x; As[ac + 5][ar] = a1.y;
    As[ac + 6][ar] = a1.z; As[ac + 7][ar] = a1.w;
    *(float4*)&Bs[br][bswz(bc)]     = b0;
    *(float4*)&Bs[br][bswz(bc + 4)] = b1;
    __syncthreads();
    #pragma unroll
    for (int kk = 0; kk < BK; ++kk) {
      float a[8], bb[8];
      *(float4*)&a[0]  = *(const float4*)&As[kk][ty * 8];
      *(float4*)&a[4]  = *(const float4*)&As[kk][ty * 8 + 4];
      *(float4*)&bb[0] = *(const float4*)&Bs[kk][bswz(tx * 8)];
      *(float4*)&bb[4] = *(const float4*)&Bs[kk][bswz(tx * 8 + 4)];
      #pragma unroll
      for (int i = 0; i < 8; ++i)
        #pragma unroll
        for (int j = 0; j < 8; ++j)
          acc[i][j] = fmaf(a[i], bb[j], acc[i][j]);
    }
    __syncthreads();
  }

  #pragma unroll
  for (int i = 0; i < 8; ++i) {
    const size_t r = (size_t)(row0 + ty * 8 + i) * HH;
    #pragma unroll
    for (int j = 0; j < 8; j += 4) {
      float4 v;
      v.x = acc[i][j + 0] + bias[col0 + tx * 8 + j + 0];
      v.y = acc[i][j + 1] + bias[col0 + tx * 8 + j + 1];
      v.z = acc[i][j + 2] + bias[col0 + tx * 8 + j + 2];
      v.w = acc[i][j + 3] + bias[col0 + tx * 8 + j + 3];
      *(float4*)&C[r + col0 + tx * 8 + j] = v;
    }
  }
}

extern "C" void kernel_launch(void* const* d_in, const int* in_sizes, int n_in,
                              void* d_out, int out_size, void* d_ws, size_t ws_size,
                              hipStream_t stream) {
  const float* x    = (const float*)d_in[0];
  const float* c_in = (const float*)d_in[1];
  const float* h_in = (const float*)d_in[2];
  const float* W    = (const float*)d_in[3];
  const float* b    = (const float*)d_in[4];
  const float* Wout = (const float*)d_in[5];
  const float* bout = (const float*)d_in[6];
  float* out = (float*)d_out;

  // ws layout: hbuf [2*H u64, 16KB] | Hs [T*H floats, 32MB]
  u64* hbuf = (u64*)d_ws;
  float* Hs = (float*)(hbuf + 2 * HH);
  float* out_tail = out + (size_t)T_STEPS * HH;

  // Tags must start at 0 every launch (graph replays reuse ws).
  hipMemsetAsync(hbuf, 0, 2 * HH * sizeof(u64), stream);

  void* args[] = {(void*)&x, (void*)&c_in, (void*)&h_in, (void*)&W, (void*)&b,
                  (void*)&Hs, (void*)&hbuf, (void*)&out_tail};
  hipLaunchCooperativeKernel((void*)lstm_scan, dim3(NWG), dim3(NTHR),
                             args, 0, stream);

  out_gemm<<<dim3(HH / BN, T_STEPS / BM), 256, 0, stream>>>(Hs, Wout, bout, out);
}

// Round 12
// 13416.029 us; speedup vs baseline: 2.4226x; 2.4226x over previous
//
#include <hip/hip_runtime.h>

#define T_STEPS 8192
#define DD 1024
#define HH 1024
#define NWG 256
#define NTHR 512
#define SCOPE_AGENT __HIP_MEMORY_SCOPE_AGENT
typedef unsigned long long u64;

// XOR swizzle (float index) so the 4 segs of a wave hit distinct bank quads
// when broadcasting 16B chunks to 16 lanes each.
__device__ __forceinline__ int swz(int k) { return k ^ ((((k) >> 6) & 3) << 2); }

__device__ __forceinline__ float ftanh(float v) {
  return 2.f / (1.f + __expf(-2.f * v)) - 1.f;
}

// ROUND-10 PROVEN SCAN STRUCTURE (12.98 ms) + critical-path micro-bundle:
//   (1) 4-way split accumulators in both dots (64-deep FMA chain -> 4x16);
//   (2) s_setprio(1) around the h-wave post-detect segment and wave0's E.
// Schedule/sync/poll timing untouched — r4/r8/r11 all proved that moving the
// poll arrival in either direction causes agent-scope retry storms.
__global__ __launch_bounds__(NTHR, 1) void lstm_scan(
    const float* __restrict__ x, const float* __restrict__ c_in,
    const float* __restrict__ h_in, const float* __restrict__ W,
    const float* __restrict__ b, float* __restrict__ Hs,  // [T][H] = h_1..h_T
    u64* __restrict__ hbuf,         // [2][H] tagged ping-pong (memset 0)
    float* __restrict__ out_tail)   // c_last | h_last
{
  const int g = blockIdx.x, tid = threadIdx.x;
  const int lane = tid & 63, wave = tid >> 6;
  const int col = tid & 15, seg = tid >> 4;
  const int gate = col >> 2, hi = col & 3;
  const int cg = gate * HH + g * 4 + hi;

  __shared__ float Wl[32768];       // 128 KB packed weight slice
  __shared__ float xb[DD];          // swizzled x_t
  __shared__ float hb[HH];          // swizzled h_{t-1} (per-wave chunks)
  __shared__ float partial[8][16];  // per-wave column partials

  float c_reg = 0.f, hlast = 0.f;

  // Publish h_0 immediately (slot 0, tag 1).
  if (tid < 4) {
    const float h0 = h_in[g * 4 + tid];
    c_reg = c_in[g * 4 + tid];
    const u64 pv = ((u64)1u << 32) | (u64)__float_as_uint(h0);
    __hip_atomic_store(&hbuf[g * 4 + tid], pv, __ATOMIC_RELAXED, SCOPE_AGENT);
  }

  // One-time weight staging: 64 strided global loads -> packed LDS.
  #pragma unroll
  for (int j = 0; j < 16; ++j) {
    float4 v;
    v.x = W[(size_t)(seg * 64 + j * 4 + 0) * (4 * HH) + cg];
    v.y = W[(size_t)(seg * 64 + j * 4 + 1) * (4 * HH) + cg];
    v.z = W[(size_t)(seg * 64 + j * 4 + 2) * (4 * HH) + cg];
    v.w = W[(size_t)(seg * 64 + j * 4 + 3) * (4 * HH) + cg];
    *(float4*)&Wl[(wave * 16 + j) * 256 + lane * 4] = v;
  }

  // Loop-invariant bias for this thread's column (used by wave 0 only).
  const float bias_reg = b[((lane & 15) >> 2) * HH + g * 4 + (lane & 3)];

  // Prefetch x_1 into registers.
  float xv0 = x[tid], xv1 = x[tid + 512];

  __syncthreads();  // Wl ready

  const bool is_x = (wave < 4);

  for (int t = 1; t <= T_STEPS; ++t) {
    // A: stage x_t from prefetch regs.
    xb[swz(tid)]       = xv0;
    xb[swz(tid + 512)] = xv1;
    __syncthreads();  // xb ready; partial[] + xb reuse guarded

    // Prefetch x_{t+1} (non-blocking; consumed at next A).
    if (t < T_STEPS) {
      const float* xn = x + (size_t)t * DD;
      xv0 = xn[tid];
      xv1 = xn[tid + 512];
    }

    if (is_x) {
      // x-half dot over segs 0..15 (4-way split accumulators).
      const int sw = (seg & 3) << 2;
      float q0 = 0.f, q1 = 0.f, q2 = 0.f, q3 = 0.f;
      #pragma unroll
      for (int j4 = 0; j4 < 4; ++j4) {
        const float4 w0 = *(const float4*)&Wl[(wave * 16 + j4 * 4 + 0) * 256 + lane * 4];
        const float4 x0 = *(const float4*)&xb[(seg * 64 + (j4 * 4 + 0) * 4) ^ sw];
        q0 = fmaf(x0.x, w0.x, q0); q0 = fmaf(x0.y, w0.y, q0);
        q0 = fmaf(x0.z, w0.z, q0); q0 = fmaf(x0.w, w0.w, q0);
        const float4 w1 = *(const float4*)&Wl[(wave * 16 + j4 * 4 + 1) * 256 + lane * 4];
        const float4 x1 = *(const float4*)&xb[(seg * 64 + (j4 * 4 + 1) * 4) ^ sw];
        q1 = fmaf(x1.x, w1.x, q1); q1 = fmaf(x1.y, w1.y, q1);
        q1 = fmaf(x1.z, w1.z, q1); q1 = fmaf(x1.w, w1.w, q1);
        const float4 w2 = *(const float4*)&Wl[(wave * 16 + j4 * 4 + 2) * 256 + lane * 4];
        const float4 x2 = *(const float4*)&xb[(seg * 64 + (j4 * 4 + 2) * 4) ^ sw];
        q2 = fmaf(x2.x, w2.x, q2); q2 = fmaf(x2.y, w2.y, q2);
        q2 = fmaf(x2.z, w2.z, q2); q2 = fmaf(x2.w, w2.w, q2);
        const float4 w3 = *(const float4*)&Wl[(wave * 16 + j4 * 4 + 3) * 256 + lane * 4];
        const float4 x3 = *(const float4*)&xb[(seg * 64 + (j4 * 4 + 3) * 4) ^ sw];
        q3 = fmaf(x3.x, w3.x, q3); q3 = fmaf(x3.y, w3.y, q3);
        q3 = fmaf(x3.z, w3.z, q3); q3 = fmaf(x3.w, w3.w, q3);
      }
      float p = (q0 + q1) + (q2 + q3);
      p += __shfl_xor(p, 16);
      p += __shfl_xor(p, 32);
      if (lane < 16) partial[wave][lane] = p;
    } else {
      // h-wave: poll own 256-atom chunk (4/lane), no sleep, stale-only retry.
      const u64* hp = hbuf + ((t - 1) & 1) * HH;
      const int cb = (wave - 4) * 256;
      const unsigned tg = (unsigned)t;
      u64 a0 = __hip_atomic_load(&hp[cb + lane],       __ATOMIC_RELAXED, SCOPE_AGENT);
      u64 a1 = __hip_atomic_load(&hp[cb + 64 + lane],  __ATOMIC_RELAXED, SCOPE_AGENT);
      u64 a2 = __hip_atomic_load(&hp[cb + 128 + lane], __ATOMIC_RELAXED, SCOPE_AGENT);
      u64 a3 = __hip_atomic_load(&hp[cb + 192 + lane], __ATOMIC_RELAXED, SCOPE_AGENT);
      bool r0 = (unsigned)(a0 >> 32) >= tg;
      bool r1 = (unsigned)(a1 >> 32) >= tg;
      bool r2 = (unsigned)(a2 >> 32) >= tg;
      bool r3 = (unsigned)(a3 >> 32) >= tg;
      while (!(r0 & r1 & r2 & r3)) {
        if (!r0) { a0 = __hip_atomic_load(&hp[cb + lane],       __ATOMIC_RELAXED, SCOPE_AGENT); r0 = (unsigned)(a0 >> 32) >= tg; }
        if (!r1) { a1 = __hip_atomic_load(&hp[cb + 64 + lane],  __ATOMIC_RELAXED, SCOPE_AGENT); r1 = (unsigned)(a1 >> 32) >= tg; }
        if (!r2) { a2 = __hip_atomic_load(&hp[cb + 128 + lane], __ATOMIC_RELAXED, SCOPE_AGENT); r2 = (unsigned)(a2 >> 32) >= tg; }
        if (!r3) { a3 = __hip_atomic_load(&hp[cb + 192 + lane], __ATOMIC_RELAXED, SCOPE_AGENT); r3 = (unsigned)(a3 >> 32) >= tg; }
      }
      // Detected: boost priority through the critical segment.
      __builtin_amdgcn_s_setprio(1);
      hb[swz(cb + lane)]       = __uint_as_float((unsigned)a0);
      hb[swz(cb + 64 + lane)]  = __uint_as_float((unsigned)a1);
      hb[swz(cb + 128 + lane)] = __uint_as_float((unsigned)a2);
      hb[swz(cb + 192 + lane)] = __uint_as_float((unsigned)a3);
      asm volatile("s_waitcnt lgkmcnt(0)" ::: "memory");
      // h-half dot over own chunk (4-way split accumulators).
      const int s2 = seg - 16;
      const int sw2 = (s2 & 3) << 2;
      float q0 = 0.f, q1 = 0.f, q2 = 0.f, q3 = 0.f;
      #pragma unroll
      for (int j4 = 0; j4 < 4; ++j4) {
        const float4 w0 = *(const float4*)&Wl[(wave * 16 + j4 * 4 + 0) * 256 + lane * 4];
        const float4 h0 = *(const float4*)&hb[(s2 * 64 + (j4 * 4 + 0) * 4) ^ sw2];
        q0 = fmaf(h0.x, w0.x, q0); q0 = fmaf(h0.y, w0.y, q0);
        q0 = fmaf(h0.z, w0.z, q0); q0 = fmaf(h0.w, w0.w, q0);
        const float4 w1 = *(const float4*)&Wl[(wave * 16 + j4 * 4 + 1) * 256 + lane * 4];
        const float4 h1 = *(const float4*)&hb[(s2 * 64 + (j4 * 4 + 1) * 4) ^ sw2];
        q1 = fmaf(h1.x, w1.x, q1); q1 = fmaf(h1.y, w1.y, q1);
        q1 = fmaf(h1.z, w1.z, q1); q1 = fmaf(h1.w, w1.w, q1);
        const float4 w2 = *(const float4*)&Wl[(wave * 16 + j4 * 4 + 2) * 256 + lane * 4];
        const float4 h2 = *(const float4*)&hb[(s2 * 64 + (j4 * 4 + 2) * 4) ^ sw2];
        q2 = fmaf(h2.x, w2.x, q2); q2 = fmaf(h2.y, w2.y, q2);
        q2 = fmaf(h2.z, w2.z, q2); q2 = fmaf(h2.w, w2.w, q2);
        const float4 w3 = *(const float4*)&Wl[(wave * 16 + j4 * 4 + 3) * 256 + lane * 4];
        const float4 h3 = *(const float4*)&hb[(s2 * 64 + (j4 * 4 + 3) * 4) ^ sw2];
        q3 = fmaf(h3.x, w3.x, q3); q3 = fmaf(h3.y, w3.y, q3);
        q3 = fmaf(h3.z, w3.z, q3); q3 = fmaf(h3.w, w3.w, q3);
      }
      float q = (q0 + q1) + (q2 + q3);
      q += __shfl_xor(q, 16);
      q += __shfl_xor(q, 32);
      if (lane < 16) partial[wave][lane] = q;
      __builtin_amdgcn_s_setprio(0);
    }
    __syncthreads();  // all 8 partial rows ready

    // E: wave 0 combines, parallel activations on 16 lanes, publishes.
    if (wave == 0) {
      __builtin_amdgcn_s_setprio(1);
      float zsum = bias_reg;
      #pragma unroll
      for (int wv = 0; wv < 8; ++wv) zsum += partial[wv][lane & 15];
      // Uniform activation: gates i,f,o -> sigmoid (f with +1); j -> tanh
      // via tanh(z) = 2*sig(2z) - 1. One __expf, no divergence.
      const int gt = (lane & 15) >> 2;
      const float zin = (gt == 1) ? (2.f * zsum) : (gt == 2 ? zsum + 1.f : zsum);
      const float s = 1.f / (1.f + __expf(-zin));
      const float act = (gt == 1) ? (2.f * s - 1.f) : s;
      const float ig = __shfl(act, tid);        // lanes 0..3 gather their gates
      const float tj = __shfl(act, tid + 4);
      const float fg = __shfl(act, tid + 8);
      const float og = __shfl(act, tid + 12);
      if (tid < 4) {
        const float nc = c_reg * fg + ig * tj;
        const float nh = ftanh(nc) * og;        // single serial transcendental
        c_reg = nc; hlast = nh;
        const u64 pv = ((u64)(unsigned)(t + 1) << 32) | (u64)__float_as_uint(nh);
        __hip_atomic_store(&hbuf[(t & 1) * HH + g * 4 + tid], pv,
                           __ATOMIC_RELAXED, SCOPE_AGENT);
        Hs[(size_t)(t - 1) * HH + g * 4 + tid] = nh;  // fire-and-forget
      }
      __builtin_amdgcn_s_setprio(0);
    }
  }

  if (tid < 4) {
    out_tail[g * 4 + tid]      = c_reg;   // c_last
    out_tail[HH + g * 4 + tid] = hlast;   // h_last
  }
}

// output = hs @ W_out + b_out. fp32 GEMM, 128x128 tile, 8x8/thread, BK=16.
// (r10 proven: per-float4 involution swizzle on Bs; As transposed.)
#define BM 128
#define BN 128
#define BK 16
__device__ __forceinline__ int bswz(int c) { return c ^ (((c >> 5) & 1) << 2); }

__global__ __launch_bounds__(256, 2) void out_gemm(
    const float* __restrict__ A,    // hs [8192][1024]
    const float* __restrict__ Bw,   // W_out [1024][1024]
    const float* __restrict__ bias,
    float* __restrict__ C)          // [8192][1024]
{
  __shared__ float As[BK][BM + 4];
  __shared__ float Bs[BK][BN + 4];
  const int tid = threadIdx.x;
  const int row0 = blockIdx.y * BM, col0 = blockIdx.x * BN;
  const int tx = tid & 15, ty = tid >> 4;

  const int ar = tid >> 1;
  const int ac = (tid & 1) * 8;
  const int br = tid >> 4;
  const int bc = (tid & 15) * 8;

  float acc[8][8];
  #pragma unroll
  for (int i = 0; i < 8; ++i)
    #pragma unroll
    for (int j = 0; j < 8; ++j) acc[i][j] = 0.f;

  for (int k0 = 0; k0 < HH; k0 += BK) {
    const float4 a0 = *(const float4*)&A[(size_t)(row0 + ar) * HH + k0 + ac];
    const float4 a1 = *(const float4*)&A[(size_t)(row0 + ar) * HH + k0 + ac + 4];
    const float4 b0 = *(const float4*)&Bw[(size_t)(k0 + br) * HH + col0 + bc];
    const float4 b1 = *(const float4*)&Bw[(size_t)(k0 + br) * HH + col0 + bc + 4];
    As[ac + 0][ar] = a0.x; As[ac + 1][ar] = a0.y;
    As[ac + 2][ar] = a0.z; As[ac + 3][ar] = a0.w;
    As[ac + 4][ar] = a1.x; As[ac + 5][ar] = a1.y;
    As[ac + 6][ar] = a1.z; As[ac + 7][ar] = a1.w;
    *(float4*)&Bs[br][bswz(bc)]     = b0;
    *(float4*)&Bs[br][bswz(bc + 4)] = b1;
    __syncthreads();
    #pragma unroll
    for (int kk = 0; kk < BK; ++kk) {
      float a[8], bb[8];
      *(float4*)&a[0]  = *(const float4*)&As[kk][ty * 8];
      *(float4*)&a[4]  = *(const float4*)&As[kk][ty * 8 + 4];
      *(float4*)&bb[0] = *(const float4*)&Bs[kk][bswz(tx * 8)];
      *(float4*)&bb[4] = *(const float4*)&Bs[kk][bswz(tx * 8 + 4)];
      #pragma unroll
      for (int i = 0; i < 8; ++i)
        #pragma unroll
        for (int j = 0; j < 8; ++j)
          acc[i][j] = fmaf(a[i], bb[j], acc[i][j]);
    }
    __syncthreads();
  }

  #pragma unroll
  for (int i = 0; i < 8; ++i) {
    const size_t r = (size_t)(row0 + ty * 8 + i) * HH;
    #pragma unroll
    for (int j = 0; j < 8; j += 4) {
      float4 v;
      v.x = acc[i][j + 0] + bias[col0 + tx * 8 + j + 0];
      v.y = acc[i][j + 1] + bias[col0 + tx * 8 + j + 1];
      v.z = acc[i][j + 2] + bias[col0 + tx * 8 + j + 2];
      v.w = acc[i][j + 3] + bias[col0 + tx * 8 + j + 3];
      *(float4*)&C[r + col0 + tx * 8 + j] = v;
    }
  }
}

extern "C" void kernel_launch(void* const* d_in, const int* in_sizes, int n_in,
                              void* d_out, int out_size, void* d_ws, size_t ws_size,
                              hipStream_t stream) {
  const float* x    = (const float*)d_in[0];
  const float* c_in = (const float*)d_in[1];
  const float* h_in = (const float*)d_in[2];
  const float* W    = (const float*)d_in[3];
  const float* b    = (const float*)d_in[4];
  const float* Wout = (const float*)d_in[5];
  const float* bout = (const float*)d_in[6];
  float* out = (float*)d_out;

  // ws layout: hbuf [2*H u64, 16KB] | Hs [T*H floats, 32MB]
  u64* hbuf = (u64*)d_ws;
  float* Hs = (float*)(hbuf + 2 * HH);
  float* out_tail = out + (size_t)T_STEPS * HH;

  // Tags must start at 0 every launch (graph replays reuse ws).
  hipMemsetAsync(hbuf, 0, 2 * HH * sizeof(u64), stream);

  void* args[] = {(void*)&x, (void*)&c_in, (void*)&h_in, (void*)&W, (void*)&b,
                  (void*)&Hs, (void*)&hbuf, (void*)&out_tail};
  hipLaunchCooperativeKernel((void*)lstm_scan, dim3(NWG), dim3(NTHR),
                             args, 0, stream);

  out_gemm<<<dim3(HH / BN, T_STEPS / BM), 256, 0, stream>>>(Hs, Wout, bout, out);
}

// Round 13
// 12992.995 us; speedup vs baseline: 2.5015x; 1.0326x over previous
//
#include <hip/hip_runtime.h>

#define T_STEPS 8192
#define DD 1024
#define HH 1024
#define NWG 256
#define NTHR 512
#define SCOPE_AGENT __HIP_MEMORY_SCOPE_AGENT
typedef unsigned long long u64;

// XOR swizzle (float index) so the 4 segs of a wave hit distinct bank quads
// when broadcasting 16B chunks to 16 lanes each.
__device__ __forceinline__ int swz(int k) { return k ^ ((((k) >> 6) & 3) << 2); }

__device__ __forceinline__ float fsig(float v) {
  return 1.f / (1.f + __expf(-v));
}
__device__ __forceinline__ float ftanh(float v) {
  return 2.f / (1.f + __expf(-2.f * v)) - 1.f;
}

// FINAL: ROUND-10 PROVEN SCAN (12.97-12.98 ms, twice). Equilibrium structure:
// poll arrival (after x-dot) matches publish visibility, so the first poll
// usually hits. Perturbations in EITHER direction regressed:
//   r4 early-poll ✗, r5 VGPR-weights ✗ (spill), r8 full-decouple ✗ (retry
//   storm), r11 per-element tail ✗ (retry storm), r12 split-acc+setprio ✗.
// Residual ~1.56us/step = 2 dependent cross-XCD L3 round trips + stage/dot/
// combine/gates + straggler-max over 256 WGs. No resource saturated.
__global__ __launch_bounds__(NTHR, 1) void lstm_scan(
    const float* __restrict__ x, const float* __restrict__ c_in,
    const float* __restrict__ h_in, const float* __restrict__ W,
    const float* __restrict__ b, float* __restrict__ Hs,  // [T][H] = h_1..h_T
    u64* __restrict__ hbuf,         // [2][H] tagged ping-pong (memset 0)
    float* __restrict__ out_tail)   // c_last | h_last
{
  const int g = blockIdx.x, tid = threadIdx.x;
  const int lane = tid & 63, wave = tid >> 6;
  const int col = tid & 15, seg = tid >> 4;
  const int gate = col >> 2, hi = col & 3;
  const int cg = gate * HH + g * 4 + hi;

  __shared__ float Wl[32768];       // 128 KB packed weight slice
  __shared__ float xb[DD];          // swizzled x_t
  __shared__ float hb[HH];          // swizzled h_{t-1} (per-wave chunks)
  __shared__ float partial[8][16];  // per-wave column partials

  float c_reg = 0.f, hlast = 0.f;

  // Publish h_0 immediately (slot 0, tag 1).
  if (tid < 4) {
    const float h0 = h_in[g * 4 + tid];
    c_reg = c_in[g * 4 + tid];
    const u64 pv = ((u64)1u << 32) | (u64)__float_as_uint(h0);
    __hip_atomic_store(&hbuf[g * 4 + tid], pv, __ATOMIC_RELAXED, SCOPE_AGENT);
  }

  // One-time weight staging: 64 strided global loads -> packed LDS.
  #pragma unroll
  for (int j = 0; j < 16; ++j) {
    float4 v;
    v.x = W[(size_t)(seg * 64 + j * 4 + 0) * (4 * HH) + cg];
    v.y = W[(size_t)(seg * 64 + j * 4 + 1) * (4 * HH) + cg];
    v.z = W[(size_t)(seg * 64 + j * 4 + 2) * (4 * HH) + cg];
    v.w = W[(size_t)(seg * 64 + j * 4 + 3) * (4 * HH) + cg];
    *(float4*)&Wl[(wave * 16 + j) * 256 + lane * 4] = v;
  }

  // Loop-invariant bias for this thread's column (used by wave 0 only).
  const float bias_reg = b[((lane & 15) >> 2) * HH + g * 4 + (lane & 3)];

  // Prefetch x_1 into registers.
  float xv0 = x[tid], xv1 = x[tid + 512];

  __syncthreads();  // Wl ready

  const bool is_x = (wave < 4);

  for (int t = 1; t <= T_STEPS; ++t) {
    // A: stage x_t from prefetch regs.
    xb[swz(tid)]       = xv0;
    xb[swz(tid + 512)] = xv1;
    __syncthreads();  // xb ready; partial[] + xb reuse guarded

    // Prefetch x_{t+1} (non-blocking; consumed at next A).
    if (t < T_STEPS) {
      const float* xn = x + (size_t)t * DD;
      xv0 = xn[tid];
      xv1 = xn[tid + 512];
    }

    if (is_x) {
      // x-half dot over segs 0..15.
      float p = 0.f;
      #pragma unroll
      for (int j = 0; j < 16; ++j) {
        const float4 wv = *(const float4*)&Wl[(wave * 16 + j) * 256 + lane * 4];
        const float4 xv = *(const float4*)&xb[(seg * 64 + j * 4) ^ ((seg & 3) << 2)];
        p = fmaf(xv.x, wv.x, p); p = fmaf(xv.y, wv.y, p);
        p = fmaf(xv.z, wv.z, p); p = fmaf(xv.w, wv.w, p);
      }
      p += __shfl_xor(p, 16);
      p += __shfl_xor(p, 32);
      if (lane < 16) partial[wave][lane] = p;
    } else {
      // h-wave: poll own 256-atom chunk (4/lane), no sleep, stale-only retry.
      const u64* hp = hbuf + ((t - 1) & 1) * HH;
      const int cb = (wave - 4) * 256;
      const unsigned tg = (unsigned)t;
      u64 a0 = __hip_atomic_load(&hp[cb + lane],       __ATOMIC_RELAXED, SCOPE_AGENT);
      u64 a1 = __hip_atomic_load(&hp[cb + 64 + lane],  __ATOMIC_RELAXED, SCOPE_AGENT);
      u64 a2 = __hip_atomic_load(&hp[cb + 128 + lane], __ATOMIC_RELAXED, SCOPE_AGENT);
      u64 a3 = __hip_atomic_load(&hp[cb + 192 + lane], __ATOMIC_RELAXED, SCOPE_AGENT);
      bool r0 = (unsigned)(a0 >> 32) >= tg;
      bool r1 = (unsigned)(a1 >> 32) >= tg;
      bool r2 = (unsigned)(a2 >> 32) >= tg;
      bool r3 = (unsigned)(a3 >> 32) >= tg;
      while (!(r0 & r1 & r2 & r3)) {
        if (!r0) { a0 = __hip_atomic_load(&hp[cb + lane],       __ATOMIC_RELAXED, SCOPE_AGENT); r0 = (unsigned)(a0 >> 32) >= tg; }
        if (!r1) { a1 = __hip_atomic_load(&hp[cb + 64 + lane],  __ATOMIC_RELAXED, SCOPE_AGENT); r1 = (unsigned)(a1 >> 32) >= tg; }
        if (!r2) { a2 = __hip_atomic_load(&hp[cb + 128 + lane], __ATOMIC_RELAXED, SCOPE_AGENT); r2 = (unsigned)(a2 >> 32) >= tg; }
        if (!r3) { a3 = __hip_atomic_load(&hp[cb + 192 + lane], __ATOMIC_RELAXED, SCOPE_AGENT); r3 = (unsigned)(a3 >> 32) >= tg; }
      }
      // Stage own chunk (2 lanes/bank after swizzle -> free).
      hb[swz(cb + lane)]       = __uint_as_float((unsigned)a0);
      hb[swz(cb + 64 + lane)]  = __uint_as_float((unsigned)a1);
      hb[swz(cb + 128 + lane)] = __uint_as_float((unsigned)a2);
      hb[swz(cb + 192 + lane)] = __uint_as_float((unsigned)a3);
      // Same-wave LDS write->read: lgkmcnt(0) is sufficient, no barrier.
      asm volatile("s_waitcnt lgkmcnt(0)" ::: "memory");
      // h-half dot over own chunk (segs s2 = (wave-4)*4 + (lane>>4)).
      const int s2 = seg - 16;
      float q = 0.f;
      #pragma unroll
      for (int j = 0; j < 16; ++j) {
        const float4 wv = *(const float4*)&Wl[(wave * 16 + j) * 256 + lane * 4];
        const float4 hv = *(const float4*)&hb[(s2 * 64 + j * 4) ^ ((s2 & 3) << 2)];
        q = fmaf(hv.x, wv.x, q); q = fmaf(hv.y, wv.y, q);
        q = fmaf(hv.z, wv.z, q); q = fmaf(hv.w, wv.w, q);
      }
      q += __shfl_xor(q, 16);
      q += __shfl_xor(q, 32);
      if (lane < 16) partial[wave][lane] = q;
    }
    __syncthreads();  // all 8 partial rows ready

    // E: wave 0 combines, parallel activations on 16 lanes, publishes.
    if (wave == 0) {
      float zsum = bias_reg;
      #pragma unroll
      for (int wv = 0; wv < 8; ++wv) zsum += partial[wv][lane & 15];
      // Uniform activation: gates i,f,o -> sigmoid (f with +1); j -> tanh
      // via tanh(z) = 2*sig(2z) - 1. One __expf, no divergence.
      const int gt = (lane & 15) >> 2;
      const float zin = (gt == 1) ? (2.f * zsum) : (gt == 2 ? zsum + 1.f : zsum);
      const float s = 1.f / (1.f + __expf(-zin));
      const float act = (gt == 1) ? (2.f * s - 1.f) : s;
      const float ig = __shfl(act, tid);        // lanes 0..3 gather their gates
      const float tj = __shfl(act, tid + 4);
      const float fg = __shfl(act, tid + 8);
      const float og = __shfl(act, tid + 12);
      if (tid < 4) {
        const float nc = c_reg * fg + ig * tj;
        const float nh = ftanh(nc) * og;        // single serial transcendental
        c_reg = nc; hlast = nh;
        const u64 pv = ((u64)(unsigned)(t + 1) << 32) | (u64)__float_as_uint(nh);
        __hip_atomic_store(&hbuf[(t & 1) * HH + g * 4 + tid], pv,
                           __ATOMIC_RELAXED, SCOPE_AGENT);
        Hs[(size_t)(t - 1) * HH + g * 4 + tid] = nh;  // fire-and-forget
      }
    }
  }

  if (tid < 4) {
    out_tail[g * 4 + tid]      = c_reg;   // c_last
    out_tail[HH + g * 4 + tid] = hlast;   // h_last
  }
}

// output = hs @ W_out + b_out. fp32 GEMM, 128x128 tile, 8x8/thread, BK=16.
// (r10 proven: per-float4 involution swizzle on Bs; As transposed.)
#define BM 128
#define BN 128
#define BK 16
__device__ __forceinline__ int bswz(int c) { return c ^ (((c >> 5) & 1) << 2); }

__global__ __launch_bounds__(256, 2) void out_gemm(
    const float* __restrict__ A,    // hs [8192][1024]
    const float* __restrict__ Bw,   // W_out [1024][1024]
    const float* __restrict__ bias,
    float* __restrict__ C)          // [8192][1024]
{
  __shared__ float As[BK][BM + 4];
  __shared__ float Bs[BK][BN + 4];
  const int tid = threadIdx.x;
  const int row0 = blockIdx.y * BM, col0 = blockIdx.x * BN;
  const int tx = tid & 15, ty = tid >> 4;

  const int ar = tid >> 1;
  const int ac = (tid & 1) * 8;
  const int br = tid >> 4;
  const int bc = (tid & 15) * 8;

  float acc[8][8];
  #pragma unroll
  for (int i = 0; i < 8; ++i)
    #pragma unroll
    for (int j = 0; j < 8; ++j) acc[i][j] = 0.f;

  for (int k0 = 0; k0 < HH; k0 += BK) {
    const float4 a0 = *(const float4*)&A[(size_t)(row0 + ar) * HH + k0 + ac];
    const float4 a1 = *(const float4*)&A[(size_t)(row0 + ar) * HH + k0 + ac + 4];
    const float4 b0 = *(const float4*)&Bw[(size_t)(k0 + br) * HH + col0 + bc];
    const float4 b1 = *(const float4*)&Bw[(size_t)(k0 + br) * HH + col0 + bc + 4];
    As[ac + 0][ar] = a0.x; As[ac + 1][ar] = a0.y;
    As[ac + 2][ar] = a0.z; As[ac + 3][ar] = a0.w;
    As[ac + 4][ar] = a1.x; As[ac + 5][ar] = a1.y;
    As[ac + 6][ar] = a1.z; As[ac + 7][ar] = a1.w;
    *(float4*)&Bs[br][bswz(bc)]     = b0;
    *(float4*)&Bs[br][bswz(bc + 4)] = b1;
    __syncthreads();
    #pragma unroll
    for (int kk = 0; kk < BK; ++kk) {
      float a[8], bb[8];
      *(float4*)&a[0]  = *(const float4*)&As[kk][ty * 8];
      *(float4*)&a[4]  = *(const float4*)&As[kk][ty * 8 + 4];
      *(float4*)&bb[0] = *(const float4*)&Bs[kk][bswz(tx * 8)];
      *(float4*)&bb[4] = *(const float4*)&Bs[kk][bswz(tx * 8 + 4)];
      #pragma unroll
      for (int i = 0; i < 8; ++i)
        #pragma unroll
        for (int j = 0; j < 8; ++j)
          acc[i][j] = fmaf(a[i], bb[j], acc[i][j]);
    }
    __syncthreads();
  }

  #pragma unroll
  for (int i = 0; i < 8; ++i) {
    const size_t r = (size_t)(row0 + ty * 8 + i) * HH;
    #pragma unroll
    for (int j = 0; j < 8; j += 4) {
      float4 v;
      v.x = acc[i][j + 0] + bias[col0 + tx * 8 + j + 0];
      v.y = acc[i][j + 1] + bias[col0 + tx * 8 + j + 1];
      v.z = acc[i][j + 2] + bias[col0 + tx * 8 + j + 2];
      v.w = acc[i][j + 3] + bias[col0 + tx * 8 + j + 3];
      *(float4*)&C[r + col0 + tx * 8 + j] = v;
    }
  }
}

extern "C" void kernel_launch(void* const* d_in, const int* in_sizes, int n_in,
                              void* d_out, int out_size, void* d_ws, size_t ws_size,
                              hipStream_t stream) {
  const float* x    = (const float*)d_in[0];
  const float* c_in = (const float*)d_in[1];
  const float* h_in = (const float*)d_in[2];
  const float* W    = (const float*)d_in[3];
  const float* b    = (const float*)d_in[4];
  const float* Wout = (const float*)d_in[5];
  const float* bout = (const float*)d_in[6];
  float* out = (float*)d_out;

  // ws layout: hbuf [2*H u64, 16KB] | Hs [T*H floats, 32MB]
  u64* hbuf = (u64*)d_ws;
  float* Hs = (float*)(hbuf + 2 * HH);
  float* out_tail = out + (size_t)T_STEPS * HH;

  // Tags must start at 0 every launch (graph replays reuse ws).
  hipMemsetAsync(hbuf, 0, 2 * HH * sizeof(u64), stream);

  void* args[] = {(void*)&x, (void*)&c_in, (void*)&h_in, (void*)&W, (void*)&b,
                  (void*)&Hs, (void*)&hbuf, (void*)&out_tail};
  hipLaunchCooperativeKernel((void*)lstm_scan, dim3(NWG), dim3(NTHR),
                             args, 0, stream);

  out_gemm<<<dim3(HH / BN, T_STEPS / BM), 256, 0, stream>>>(Hs, Wout, bout, out);
}